// Round 3
// baseline (155.426 us; speedup 1.0000x reference)
//
#include <hip/hip_runtime.h>
#include <hip/hip_cooperative_groups.h>

namespace cg = cooperative_groups;

#define LOG2E 1.4426950408889634f
#define BN_EPS 1e-5f

typedef float f32x2 __attribute__((ext_vector_type(2)));
typedef float f32x4 __attribute__((ext_vector_type(4)));

__device__ __forceinline__ float sigf(float x){
    return __builtin_amdgcn_rcpf(1.f + __builtin_amdgcn_exp2f(-LOG2E * x));
}
// sig(a)*tanh(b) with a single rcp: A=e^a, B=e^{2b} -> A(B-1)/((1+A)(B+1))
__device__ __forceinline__ float sigtanh(float a, float b){
    float A  = __builtin_amdgcn_exp2f(LOG2E * a);
    float Bv = __builtin_amdgcn_exp2f((2.f * LOG2E) * b);
    float num = A * (Bv - 1.f);
    float den = (1.f + A) * (1.f + Bv);
    return num * __builtin_amdgcn_rcpf(den);
}
__device__ __forceinline__ float relu_(float x){ return fmaxf(x, 0.f); }

__device__ __forceinline__ float wsum(float v){
    #pragma unroll
    for (int m = 32; m >= 1; m >>= 1) v += __shfl_xor(v, m, 64);
    return v;
}

__device__ constexpr int TRI(int j, int l){ return j*9 - j*(j-1)/2 + (l - j); } // j<=l, 45 entries

__device__ __forceinline__ void load_h0(const float* __restrict__ x, const float* __restrict__ emb,
                                        long row, float h0[9])
{
    const float4* xv = (const float4*)(x + row * 8);
    float4 p = xv[0];
    float4 q = xv[1];
    int idx = (int)p.x;
    float2 e = ((const float2*)emb)[idx];
    h0[0] = e.x; h0[1] = e.y;
    h0[2] = p.y; h0[3] = p.z; h0[4] = p.w;
    h0[5] = q.x; h0[6] = q.y; h0[7] = q.z; h0[8] = q.w;
}

// BN1 scale/shift from h0 moments; threads 0..17 -> LDS
__device__ __forceinline__ void bn1_from_moments(const float* __restrict__ stats,
                                                 const float* __restrict__ W1, const float* __restrict__ b1,
                                                 const float* __restrict__ g1, const float* __restrict__ be1,
                                                 float invB, float* smem_sc, float* smem_sh)
{
    if (threadIdx.x < 18){
        int k = threadIdx.x;
        float w[9];
        #pragma unroll
        for (int j = 0; j < 9; ++j) w[j] = W1[k*9 + j];
        float dot9 = 0.f, q = 0.f;
        #pragma unroll
        for (int j = 0; j < 9; ++j){
            dot9 = fmaf(w[j], stats[j], dot9);
            q = fmaf(w[j]*w[j], stats[16 + TRI(j,j)], q);
            #pragma unroll
            for (int l = j+1; l < 9; ++l)
                q = fmaf(2.f*w[j]*w[l], stats[16 + TRI(j,l)], q);
        }
        float m1  = dot9 * invB;
        float var = fmaf(-m1, m1, q * invB);
        float mu  = m1 + b1[k];
        float sc  = g1[k] * __builtin_amdgcn_rsqf(var + BN_EPS);
        smem_sc[k] = sc;
        smem_sh[k] = fmaf(-mu, sc, be1[k]);
    }
    __syncthreads();
}

__device__ __forceinline__ f32x2 mk2(float a, float b){ f32x2 r; r.x=a; r.y=b; return r; }
__device__ __forceinline__ f32x4 mk4(float a, float b, float c, float d){ f32x4 r; r.x=a; r.y=b; r.z=c; r.w=d; return r; }

struct KParams {
    const float *x, *emb, *W1, *b1, *g1, *be1, *W2, *b2, *g2, *be2;
    const float *w1f, *u1f, *c1f, *w1r, *u1r, *c1r;
    const float *w2f, *u2f, *c2f, *w2r, *u2r, *c2r;
    float* stats;
    float* out;
    int B;
};

// ============ fused cooperative kernel: moments -> BN1 -> z2 stats -> BN2 -> LSTMs ============
__global__ __launch_bounds__(256, 4) void k_fused(KParams p)
{
    cg::grid_group grid = cg::this_grid();
    const int tid = threadIdx.x;
    const long base = (long)blockIdx.x * 1024 + tid;
    const float invB = 1.f / (float)p.B;
    const bool l0 = (tid & 63) == 0;

    // ---------------- P1: h0 moments (9 sums + 45 second moments) ----------------
    {
        float s9[9], mt[45];
        #pragma unroll
        for (int j = 0; j < 9; ++j) s9[j] = 0.f;
        #pragma unroll
        for (int t = 0; t < 45; ++t) mt[t] = 0.f;

        #pragma unroll
        for (int r = 0; r < 4; ++r){
            long row = base + r * 256;
            if (row < p.B){
                float h0[9];
                load_h0(p.x, p.emb, row, h0);
                #pragma unroll
                for (int j = 0; j < 9; ++j){
                    s9[j] += h0[j];
                    #pragma unroll
                    for (int l = j; l < 9; ++l)
                        mt[TRI(j,l)] = fmaf(h0[j], h0[l], mt[TRI(j,l)]);
                }
            }
        }
        __shared__ float sm[54];
        if (tid < 54) sm[tid] = 0.f;
        __syncthreads();
        #pragma unroll
        for (int j = 0; j < 9; ++j){
            float v = wsum(s9[j]);
            if (l0) atomicAdd(&sm[j], v);
        }
        #pragma unroll
        for (int t = 0; t < 45; ++t){
            float v = wsum(mt[t]);
            if (l0) atomicAdd(&sm[9 + t], v);
        }
        __syncthreads();
        if (tid < 9)       atomicAdd(&p.stats[tid], sm[tid]);
        else if (tid < 54) atomicAdd(&p.stats[16 + tid - 9], sm[tid]);
    }

    grid.sync();

    // ---------------- P2: BN1 -> a1 -> z2 (kept in regs) + z2 stats ----------------
    float z2r[4][9];
    {
        __shared__ float s_sc[18], s_sh[18];
        bn1_from_moments(p.stats, p.W1, p.b1, p.g1, p.be1, invB, s_sc, s_sh);

        float sc1[18], sh1[18];
        #pragma unroll
        for (int k = 0; k < 18; ++k){ sc1[k] = s_sc[k]; sh1[k] = s_sh[k]; }

        float as[9], aq[9];
        #pragma unroll
        for (int k = 0; k < 9; ++k){ as[k] = 0.f; aq[k] = 0.f; }

        #pragma unroll
        for (int r = 0; r < 4; ++r){
            long row = base + r * 256;
            if (row < p.B){
                float h0[9];
                load_h0(p.x, p.emb, row, h0);
                float a1[18];
                #pragma unroll
                for (int k = 0; k < 18; ++k){
                    float s = p.b1[k];
                    #pragma unroll
                    for (int j = 0; j < 9; ++j) s = fmaf(p.W1[k*9 + j], h0[j], s);
                    a1[k] = relu_(fmaf(sc1[k], s, sh1[k]));
                }
                #pragma unroll
                for (int k = 0; k < 9; ++k){
                    float s = p.b2[k];
                    #pragma unroll
                    for (int j = 0; j < 18; ++j) s = fmaf(p.W2[k*18 + j], a1[j], s);
                    z2r[r][k] = s;
                    as[k] += s; aq[k] = fmaf(s, s, aq[k]);
                }
            } else {
                #pragma unroll
                for (int k = 0; k < 9; ++k) z2r[r][k] = 0.f;
            }
        }
        __shared__ float sm2[18];
        if (tid < 18) sm2[tid] = 0.f;
        __syncthreads();
        #pragma unroll
        for (int k = 0; k < 9; ++k){
            float s = wsum(as[k]);
            float q = wsum(aq[k]);
            if (l0){ atomicAdd(&sm2[k], s); atomicAdd(&sm2[9 + k], q); }
        }
        __syncthreads();
        if (tid < 9)       atomicAdd(&p.stats[64 + tid], sm2[tid]);
        else if (tid < 18) atomicAdd(&p.stats[80 + tid - 9], sm2[tid]);
    }

    grid.sync();

    // ---------------- P3: BN2 + biLSTM x2 + output ----------------
    float sc2[9], sh2[9];
    #pragma unroll
    for (int k = 0; k < 9; ++k){
        float mu  = p.stats[64 + k] * invB;
        float var = fmaf(-mu, mu, p.stats[80 + k] * invB);
        float sc  = p.g2[k] * __builtin_amdgcn_rsqf(var + BN_EPS);
        sc2[k] = sc;
        sh2[k] = fmaf(-mu, sc, p.be2[k]);
    }

    // LSTM1 weights packed [fwd0, fwd1, rev0, rev1]
    f32x4 W4[4], U04[4], U14[4], B4[4];
    #pragma unroll
    for (int g = 0; g < 4; ++g){
        W4[g]  = mk4(p.w1f[2*g], p.w1f[2*g+1], p.w1r[2*g], p.w1r[2*g+1]);
        U04[g] = mk4(p.u1f[(2*g)*2], p.u1f[(2*g+1)*2], p.u1r[(2*g)*2], p.u1r[(2*g+1)*2]);
        U14[g] = mk4(p.u1f[(2*g)*2+1], p.u1f[(2*g+1)*2+1], p.u1r[(2*g)*2+1], p.u1r[(2*g+1)*2+1]);
        B4[g]  = mk4(p.c1f[2*g], p.c1f[2*g+1], p.c1r[2*g], p.c1r[2*g+1]);
    }
    // LSTM2 weights packed [fwd, rev]
    f32x2 w2v[4][4], u2v[4], b2v[4];
    #pragma unroll
    for (int r = 0; r < 4; ++r){
        #pragma unroll
        for (int j = 0; j < 4; ++j) w2v[r][j] = mk2(p.w2f[4*r + j], p.w2r[4*r + j]);
        u2v[r] = mk2(p.u2f[r], p.u2r[r]);
        b2v[r] = mk2(p.c2f[r], p.c2r[r]);
    }

    #pragma unroll
    for (int r = 0; r < 4; ++r){
        long row = base + r * 256;
        if (row >= p.B) continue;

        float a2[9];
        #pragma unroll
        for (int k = 0; k < 9; ++k)
            a2[k] = relu_(fmaf(sc2[k], z2r[r][k], sh2[k]));

        // biLSTM layer 1
        f32x4 h4 = {0.f, 0.f, 0.f, 0.f};
        f32x4 c4 = {0.f, 0.f, 0.f, 0.f};
        float u_[9][4];
        #pragma unroll
        for (int s = 0; s < 9; ++s){
            const int tf = s, tr = 8 - s;
            f32x4 xt4 = mk4(a2[tf], a2[tf], a2[tr], a2[tr]);
            f32x4 hx  = mk4(h4.x, h4.x, h4.z, h4.z);
            f32x4 hy  = mk4(h4.y, h4.y, h4.w, h4.w);
            f32x4 z[4];
            #pragma unroll
            for (int g = 0; g < 4; ++g)
                z[g] = __builtin_elementwise_fma(W4[g], xt4,
                        __builtin_elementwise_fma(U04[g], hx,
                         __builtin_elementwise_fma(U14[g], hy, B4[g])));
            f32x4 icg, fs;
            #pragma unroll
            for (int c = 0; c < 4; ++c){
                icg[c] = sigtanh(z[0][c], z[2][c]);
                fs[c]  = sigf(z[1][c]);
            }
            c4 = __builtin_elementwise_fma(fs, c4, icg);
            #pragma unroll
            for (int c = 0; c < 4; ++c) h4[c] = sigtanh(z[3][c], c4[c]);
            u_[tf][0] = relu_(h4.x);
            u_[tf][1] = relu_(h4.y);
            u_[tr][2] = relu_(h4.z);
            u_[tr][3] = relu_(h4.w);
        }

        // biLSTM layer 2
        f32x2 h2 = {0.f, 0.f};
        f32x2 cc = {0.f, 0.f};
        float of[9], orr[9];
        #pragma unroll
        for (int s = 0; s < 9; ++s){
            const int tf = s, tr = 8 - s;
            f32x2 z[4];
            #pragma unroll
            for (int g = 0; g < 4; ++g){
                f32x2 acc = __builtin_elementwise_fma(u2v[g], h2, b2v[g]);
                #pragma unroll
                for (int j = 0; j < 4; ++j)
                    acc = __builtin_elementwise_fma(w2v[g][j], mk2(u_[tf][j], u_[tr][j]), acc);
                z[g] = acc;
            }
            f32x2 icg, fs;
            #pragma unroll
            for (int c = 0; c < 2; ++c){
                icg[c] = sigtanh(z[0][c], z[2][c]);
                fs[c]  = sigf(z[1][c]);
            }
            cc = __builtin_elementwise_fma(fs, cc, icg);
            float hfo = sigtanh(z[3][0], cc.x);
            float hro = sigtanh(z[3][1], cc.y);
            h2 = mk2(hfo, hro);
            of[tf]  = hfo;
            orr[tr] = hro;
        }
        float2* op = (float2*)(p.out + row * 18);
        #pragma unroll
        for (int t = 0; t < 9; ++t) op[t] = make_float2(of[t], orr[t]);
    }
}

// ============================ fallback 3-kernel path ============================
__global__ __launch_bounds__(256) void k_moments(const float* __restrict__ x, const float* __restrict__ emb,
                                                 float* __restrict__ stats, int B)
{
    float s9[9], mt[45];
    #pragma unroll
    for (int j = 0; j < 9; ++j) s9[j] = 0.f;
    #pragma unroll
    for (int t = 0; t < 45; ++t) mt[t] = 0.f;

    long base = (long)blockIdx.x * 1024 + threadIdx.x;
    #pragma unroll
    for (int r = 0; r < 4; ++r){
        long row = base + r * 256;
        if (row < B){
            float h0[9];
            load_h0(x, emb, row, h0);
            #pragma unroll
            for (int j = 0; j < 9; ++j){
                s9[j] += h0[j];
                #pragma unroll
                for (int l = j; l < 9; ++l)
                    mt[TRI(j,l)] = fmaf(h0[j], h0[l], mt[TRI(j,l)]);
            }
        }
    }
    __shared__ float sm[54];
    if (threadIdx.x < 54) sm[threadIdx.x] = 0.f;
    __syncthreads();
    bool l0 = (threadIdx.x & 63) == 0;
    #pragma unroll
    for (int j = 0; j < 9; ++j){
        float v = wsum(s9[j]);
        if (l0) atomicAdd(&sm[j], v);
    }
    #pragma unroll
    for (int t = 0; t < 45; ++t){
        float v = wsum(mt[t]);
        if (l0) atomicAdd(&sm[9 + t], v);
    }
    __syncthreads();
    if (threadIdx.x < 9)  atomicAdd(&stats[threadIdx.x], sm[threadIdx.x]);
    else if (threadIdx.x < 54) atomicAdd(&stats[16 + threadIdx.x - 9], sm[threadIdx.x]);
}

__global__ __launch_bounds__(256) void k_stats2(KParams p)
{
    __shared__ float s_sc[18], s_sh[18];
    bn1_from_moments(p.stats, p.W1, p.b1, p.g1, p.be1, 1.f/(float)p.B, s_sc, s_sh);

    float sc1[18], sh1[18];
    #pragma unroll
    for (int k = 0; k < 18; ++k){ sc1[k] = s_sc[k]; sh1[k] = s_sh[k]; }

    float as[9], aq[9];
    #pragma unroll
    for (int k = 0; k < 9; ++k){ as[k] = 0.f; aq[k] = 0.f; }

    long base = (long)blockIdx.x * 1024 + threadIdx.x;
    #pragma unroll
    for (int r = 0; r < 4; ++r){
        long row = base + r * 256;
        if (row < p.B){
            float h0[9];
            load_h0(p.x, p.emb, row, h0);
            float a1[18];
            #pragma unroll
            for (int k = 0; k < 18; ++k){
                float s = p.b1[k];
                #pragma unroll
                for (int j = 0; j < 9; ++j) s = fmaf(p.W1[k*9 + j], h0[j], s);
                a1[k] = relu_(fmaf(sc1[k], s, sh1[k]));
            }
            #pragma unroll
            for (int k = 0; k < 9; ++k){
                float s = p.b2[k];
                #pragma unroll
                for (int j = 0; j < 18; ++j) s = fmaf(p.W2[k*18 + j], a1[j], s);
                as[k] += s; aq[k] = fmaf(s, s, aq[k]);
            }
        }
    }
    __shared__ float sm[18];
    if (threadIdx.x < 18) sm[threadIdx.x] = 0.f;
    __syncthreads();
    bool l0 = (threadIdx.x & 63) == 0;
    #pragma unroll
    for (int k = 0; k < 9; ++k){
        float s = wsum(as[k]);
        float q = wsum(aq[k]);
        if (l0){ atomicAdd(&sm[k], s); atomicAdd(&sm[9 + k], q); }
    }
    __syncthreads();
    if (threadIdx.x < 9)       atomicAdd(&p.stats[64 + threadIdx.x], sm[threadIdx.x]);
    else if (threadIdx.x < 18) atomicAdd(&p.stats[80 + threadIdx.x - 9], sm[threadIdx.x]);
}

__global__ __launch_bounds__(256) void k_main_fb(KParams p)
{
    __shared__ float s_sc[18], s_sh[18];
    float invB = 1.f / (float)p.B;
    bn1_from_moments(p.stats, p.W1, p.b1, p.g1, p.be1, invB, s_sc, s_sh);

    long row = (long)blockIdx.x * 256 + threadIdx.x;
    if (row >= p.B) return;

    float h0[9];
    load_h0(p.x, p.emb, row, h0);
    float a1[18];
    #pragma unroll
    for (int k = 0; k < 18; ++k){
        float s = p.b1[k];
        #pragma unroll
        for (int j = 0; j < 9; ++j) s = fmaf(p.W1[k*9 + j], h0[j], s);
        a1[k] = relu_(fmaf(s_sc[k], s, s_sh[k]));
    }
    float a2[9];
    #pragma unroll
    for (int k = 0; k < 9; ++k){
        float s = p.b2[k];
        #pragma unroll
        for (int j = 0; j < 18; ++j) s = fmaf(p.W2[k*18 + j], a1[j], s);
        float mu  = p.stats[64 + k] * invB;
        float var = fmaf(-mu, mu, p.stats[80 + k] * invB);
        float sc  = p.g2[k] * __builtin_amdgcn_rsqf(var + BN_EPS);
        a2[k] = relu_(fmaf(sc, s - mu, p.be2[k]));
    }

    f32x4 W4[4], U04[4], U14[4], B4[4];
    #pragma unroll
    for (int g = 0; g < 4; ++g){
        W4[g]  = mk4(p.w1f[2*g], p.w1f[2*g+1], p.w1r[2*g], p.w1r[2*g+1]);
        U04[g] = mk4(p.u1f[(2*g)*2], p.u1f[(2*g+1)*2], p.u1r[(2*g)*2], p.u1r[(2*g+1)*2]);
        U14[g] = mk4(p.u1f[(2*g)*2+1], p.u1f[(2*g+1)*2+1], p.u1r[(2*g)*2+1], p.u1r[(2*g+1)*2+1]);
        B4[g]  = mk4(p.c1f[2*g], p.c1f[2*g+1], p.c1r[2*g], p.c1r[2*g+1]);
    }
    f32x4 h4 = {0.f, 0.f, 0.f, 0.f};
    f32x4 c4 = {0.f, 0.f, 0.f, 0.f};
    float u_[9][4];
    #pragma unroll
    for (int s = 0; s < 9; ++s){
        const int tf = s, tr = 8 - s;
        f32x4 xt4 = mk4(a2[tf], a2[tf], a2[tr], a2[tr]);
        f32x4 hx  = mk4(h4.x, h4.x, h4.z, h4.z);
        f32x4 hy  = mk4(h4.y, h4.y, h4.w, h4.w);
        f32x4 z[4];
        #pragma unroll
        for (int g = 0; g < 4; ++g)
            z[g] = __builtin_elementwise_fma(W4[g], xt4,
                    __builtin_elementwise_fma(U04[g], hx,
                     __builtin_elementwise_fma(U14[g], hy, B4[g])));
        f32x4 icg, fs;
        #pragma unroll
        for (int c = 0; c < 4; ++c){
            icg[c] = sigtanh(z[0][c], z[2][c]);
            fs[c]  = sigf(z[1][c]);
        }
        c4 = __builtin_elementwise_fma(fs, c4, icg);
        #pragma unroll
        for (int c = 0; c < 4; ++c) h4[c] = sigtanh(z[3][c], c4[c]);
        u_[tf][0] = relu_(h4.x);
        u_[tf][1] = relu_(h4.y);
        u_[tr][2] = relu_(h4.z);
        u_[tr][3] = relu_(h4.w);
    }

    f32x2 w2v[4][4], u2v[4], b2v[4];
    #pragma unroll
    for (int r = 0; r < 4; ++r){
        #pragma unroll
        for (int j = 0; j < 4; ++j) w2v[r][j] = mk2(p.w2f[4*r + j], p.w2r[4*r + j]);
        u2v[r] = mk2(p.u2f[r], p.u2r[r]);
        b2v[r] = mk2(p.c2f[r], p.c2r[r]);
    }
    f32x2 h2 = {0.f, 0.f};
    f32x2 cc = {0.f, 0.f};
    float of[9], orr[9];
    #pragma unroll
    for (int s = 0; s < 9; ++s){
        const int tf = s, tr = 8 - s;
        f32x2 z[4];
        #pragma unroll
        for (int g = 0; g < 4; ++g){
            f32x2 acc = __builtin_elementwise_fma(u2v[g], h2, b2v[g]);
            #pragma unroll
            for (int j = 0; j < 4; ++j)
                acc = __builtin_elementwise_fma(w2v[g][j], mk2(u_[tf][j], u_[tr][j]), acc);
            z[g] = acc;
        }
        f32x2 icg, fs;
        #pragma unroll
        for (int c = 0; c < 2; ++c){
            icg[c] = sigtanh(z[0][c], z[2][c]);
            fs[c]  = sigf(z[1][c]);
        }
        cc = __builtin_elementwise_fma(fs, cc, icg);
        float hfo = sigtanh(z[3][0], cc.x);
        float hro = sigtanh(z[3][1], cc.y);
        h2 = mk2(hfo, hro);
        of[tf]  = hfo;
        orr[tr] = hro;
    }
    float2* op = (float2*)(p.out + row * 18);
    #pragma unroll
    for (int t = 0; t < 9; ++t) op[t] = make_float2(of[t], orr[t]);
}

extern "C" void kernel_launch(void* const* d_in, const int* in_sizes, int n_in,
                              void* d_out, int out_size, void* d_ws, size_t ws_size,
                              hipStream_t stream)
{
    KParams p;
    p.x    = (const float*)d_in[0];
    p.emb  = (const float*)d_in[1];
    p.W1   = (const float*)d_in[2];
    p.b1   = (const float*)d_in[3];
    p.g1   = (const float*)d_in[4];
    p.be1  = (const float*)d_in[5];
    p.W2   = (const float*)d_in[6];
    p.b2   = (const float*)d_in[7];
    p.g2   = (const float*)d_in[8];
    p.be2  = (const float*)d_in[9];
    p.w1f  = (const float*)d_in[10];
    p.u1f  = (const float*)d_in[11];
    p.c1f  = (const float*)d_in[12];
    p.w1r  = (const float*)d_in[13];
    p.u1r  = (const float*)d_in[14];
    p.c1r  = (const float*)d_in[15];
    p.w2f  = (const float*)d_in[16];
    p.u2f  = (const float*)d_in[17];
    p.c2f  = (const float*)d_in[18];
    p.w2r  = (const float*)d_in[19];
    p.u2r  = (const float*)d_in[20];
    p.c2r  = (const float*)d_in[21];
    p.stats = (float*)d_ws;
    p.out   = (float*)d_out;
    p.B     = in_sizes[0] / 8;

    // stats layout: [0:9] sum h0, [16:61] upper-tri second moments,
    //               [64:73] sum z2, [80:89] sumsq z2
    hipMemsetAsync(d_ws, 0, 128 * sizeof(float), stream);

    int nb = (p.B + 1023) / 1024;   // 4 rows/thread, 256 threads

    bool coop_done = false;
    int dev = 0;
    hipGetDevice(&dev);
    int cus = 0;
    hipDeviceGetAttribute(&cus, hipDeviceAttributeMultiprocessorCount, dev);
    int maxb = 0;
    hipError_t oe = hipOccupancyMaxActiveBlocksPerMultiprocessor(&maxb, k_fused, 256, 0);
    if (oe == hipSuccess && cus > 0 && (long)maxb * cus >= nb){
        void* args[] = { (void*)&p };
        hipError_t e = hipLaunchCooperativeKernel((void*)k_fused, dim3(nb), dim3(256), args, 0, stream);
        coop_done = (e == hipSuccess);
    }

    if (!coop_done){
        int nb3 = (p.B + 255) / 256;
        k_moments<<<nb, 256, 0, stream>>>(p.x, p.emb, p.stats, p.B);
        k_stats2<<<nb, 256, 0, stream>>>(p);
        k_main_fb<<<nb3, 256, 0, stream>>>(p);
    }
}